// Round 5
// baseline (304.948 us; speedup 1.0000x reference)
//
#include <hip/hip_runtime.h>

#define NPTS   16384
#define NDIM   64
#define NBATCH 8
#define TB     1024
#define VPT    16      // NPTS / TB
#define NB     6144    // histogram bins (packed u16 counts, 2 per u32)
#define BPT    6       // NB / TB (even: word-aligned per thread)
#define NW     (NB/2)  // packed words
#define EPSF   0.1f
#define MINS   5
#define NCMAX  512
#define BIGI   0x3fffffff

// LDS swizzle for xs: spread per-thread-contiguous accesses across banks (bijective XOR)
__device__ __forceinline__ int phys(int i) { return i ^ ((i >> 5) & 15); }

__device__ __forceinline__ int binof(float x, float mn, float inv) {
  float fb = (x - mn) * inv;
  int b = (int)fb;
  if (fb < 0.f) b = 0;
  if (b > NB - 1) b = NB - 1;
  return b;
}
__device__ __forceinline__ int pk_get(unsigned w, int odd) {
  return (int)((w >> (odd << 4)) & 0xffffu);
}

// ---------------- transpose (B,N,D) -> (B,D,N) ----------------
__global__ void ktrans(const float* __restrict__ f, float* __restrict__ xt) {
  __shared__ float tile[64][65];
  int blk = blockIdx.x;
  int b   = blk >> 8;
  int n0  = (blk & 255) << 6;
  for (int i = threadIdx.x; i < 64 * 64; i += 256) {
    int n = i >> 6, d = i & 63;
    tile[n][d] = f[((size_t)b * NPTS + n0 + n) * NDIM + d];
  }
  __syncthreads();
  for (int i = threadIdx.x; i < 64 * 64; i += 256) {
    int d = i >> 6, n = i & 63;
    xt[((size_t)b * NDIM + d) * NPTS + n0 + n] = tile[n][d];
  }
}

// forward-scan monoid: (has core, first core val, last core val, #internal starts)
struct FS { int h; float f; float l; int c; };
__device__ __forceinline__ FS fsid() { FS r; r.h = 0; r.f = 0.f; r.l = 0.f; r.c = 0; return r; }
__device__ __forceinline__ FS fscomb(FS a, FS b) {
  FS r;
  r.h = a.h | b.h;
  r.f = a.h ? a.f : b.f;
  r.l = b.h ? b.l : a.l;
  int gap = (a.h && b.h && ((b.f - a.l) > EPSF)) ? 1 : 0;
  r.c = a.c + b.c + gap;
  return r;
}

// ---------------- per-(b,d) exact 1-D DBSCAN (2 blocks/CU) ----------------
__global__ void __launch_bounds__(TB, 8) kdbscan(const float* __restrict__ xt,
                                                 short* __restrict__ labels,
                                                 short* __restrict__ labg,
                                                 int* __restrict__ nclg) {
  const int tid  = threadIdx.x;
  const int lane = tid & 63;
  const int wid  = tid >> 6;
  const int bd   = blockIdx.x;
  const float* __restrict__ x = xt + (size_t)bd * NPTS;
  short* __restrict__ lab = labg + (size_t)bd * NPTS;   // labels by sorted position

  __shared__ float xs[NPTS];            // 64 KB (phys-swizzled); histogram aliases this pre-scatter
  __shared__ unsigned offsp[NW];        // 12 KB packed u16 bin offsets
  __shared__ float wmn[16], wmx[16];
  __shared__ unsigned wsum[16];
  __shared__ int   sh[16];  __shared__ float sf[16], sl[16]; __shared__ int sc[16];
  __shared__ int   wri[16]; __shared__ float wrv[16];
  unsigned* histp = (unsigned*)xs;      // NW packed words inside xs (dead before scatter)

  // ---- 1. load + min/max (v live only through phase 4) ----
  float v[VPT];
  float mn = INFINITY, mx = -INFINITY;
  #pragma unroll
  for (int s = 0; s < VPT; ++s) {
    v[s] = x[tid + s * TB];
    mn = fminf(mn, v[s]); mx = fmaxf(mx, v[s]);
  }
  for (int d = 1; d < 64; d <<= 1) {
    mn = fminf(mn, __shfl_xor(mn, d));
    mx = fmaxf(mx, __shfl_xor(mx, d));
  }
  if (lane == 0) { wmn[wid] = mn; wmx[wid] = mx; }
  __syncthreads();
  mn = wmn[0]; mx = wmx[0];
  for (int w = 1; w < 16; ++w) { mn = fminf(mn, wmn[w]); mx = fmaxf(mx, wmx[w]); }
  float range = mx - mn;
  float inv = (range > 0.f) ? ((float)NB / range) : 0.f;

  // ---- 2. histogram (packed u16 counts, in xs region) ----
  for (int i = tid; i < NW; i += TB) histp[i] = 0u;
  __syncthreads();
  #pragma unroll
  for (int s = 0; s < VPT; ++s) {
    int b = binof(v[s], mn, inv);
    atomicAdd(&histp[b >> 1], 1u << ((b & 1) << 4));
  }
  __syncthreads();

  // ---- 3. exclusive prefix sum -> offsp = packed bin starts ----
  unsigned loc[BPT];
  unsigned run = 0;
  const int bbase = tid * BPT;
  #pragma unroll
  for (int j = 0; j < BPT; ++j) {
    int b = bbase + j;
    unsigned c = (histp[b >> 1] >> ((b & 1) << 4)) & 0xffffu;
    loc[j] = run; run += c;
  }
  unsigned incl = run;
  for (int d = 1; d < 64; d <<= 1) {
    unsigned u = __shfl_up(incl, d);
    if (lane >= d) incl += u;
  }
  unsigned exc = __shfl_up(incl, 1);
  if (lane == 0) exc = 0u;
  if (lane == 63) wsum[wid] = incl;
  __syncthreads();
  unsigned wb = 0;
  for (int w = 0; w < wid; ++w) wb += wsum[w];
  unsigned tb0 = wb + exc;
  #pragma unroll
  for (int k = 0; k < BPT / 2; ++k) {
    unsigned a  = tb0 + loc[2 * k];
    unsigned b2 = tb0 + loc[2 * k + 1];
    offsp[(bbase >> 1) + k] = a | (b2 << 16);
  }
  __syncthreads();

  // ---- 4. scatter into bins (atomic on packed u16; offsp -> bin ends) ----
  #pragma unroll
  for (int s = 0; s < VPT; ++s) {
    int b = binof(v[s], mn, inv);
    unsigned old = atomicAdd(&offsp[b >> 1], 1u << ((b & 1) << 4));
    xs[phys(pk_get(old, b & 1))] = v[s];
  }
  __syncthreads();
  // v[] dead from here

  // ---- 5. insertion sort within each bin (disjoint ranges per thread) ----
  #pragma unroll
  for (int j = 0; j < BPT; ++j) {
    int b  = bbase + j;
    int e0 = pk_get(offsp[b >> 1], b & 1);
    int s0 = b ? pk_get(offsp[(b - 1) >> 1], (b - 1) & 1) : 0;
    for (int ii = s0 + 1; ii < e0; ++ii) {
      float key = xs[phys(ii)];
      int k = ii - 1;
      while (k >= s0 && xs[phys(k)] > key) { xs[phys(k + 1)] = xs[phys(k)]; --k; }
      xs[phys(k + 1)] = key;
    }
  }
  __syncthreads();   // xs fully sorted ascending

  // ---- 6. rolling window: core flags + FS seed + backward seed ----
  const int p0 = tid * VPT;
  float wa[9];
  #pragma unroll
  for (int k = 0; k < 9; ++k) {
    int i = p0 - 4 + k;
    wa[k] = (i < 0) ? -INFINITY : xs[phys(i)];
  }
  unsigned coremask = 0u;
  FS ch = fsid();
  int fi = BIGI; float fv = 0.f;
  #pragma unroll
  for (int s = 0; s < VPT; ++s) {
    float xi = wa[4];
    float lo = xi - EPSF, hi2 = xi + EPSF;
    bool core = false;
    #pragma unroll
    for (int t = 0; t < MINS; ++t)
      core |= (wa[4 - t] >= lo) && (wa[8 - t] <= hi2);
    if (core) {
      coremask |= (1u << s);
      if (!ch.h) { ch.h = 1; ch.f = xi; }
      else if ((xi - ch.l) > EPSF) ++ch.c;
      ch.l = xi;
      if (fi == BIGI) { fi = p0 + s; fv = xi; }
    }
    #pragma unroll
    for (int k = 0; k < 8; ++k) wa[k] = wa[k + 1];
    int nx = p0 + s + 5;
    wa[8] = (nx < NPTS) ? xs[phys(nx)] : INFINITY;
  }

  // ---- 7. FS block scan (forward) ----
  FS cur = ch;
  for (int d = 1; d < 64; d <<= 1) {
    FS u;
    u.h = __shfl_up(cur.h, d);
    u.f = __shfl_up(cur.f, d);
    u.l = __shfl_up(cur.l, d);
    u.c = __shfl_up(cur.c, d);
    FS cmb = fscomb(u, cur);
    if (lane >= d) cur = cmb;
  }
  FS exs;
  exs.h = __shfl_up(cur.h, 1);
  exs.f = __shfl_up(cur.f, 1);
  exs.l = __shfl_up(cur.l, 1);
  exs.c = __shfl_up(cur.c, 1);
  if (lane == 0) exs = fsid();
  if (lane == 63) { sh[wid] = cur.h; sf[wid] = cur.f; sl[wid] = cur.l; sc[wid] = cur.c; }
  __syncthreads();
  FS pre = fsid();
  for (int w2 = 0; w2 < wid; ++w2) {
    FS t; t.h = sh[w2]; t.f = sf[w2]; t.l = sl[w2]; t.c = sc[w2];
    pre = fscomb(pre, t);
  }
  FS sp = fscomb(pre, exs);

  // ---- 8. backward block scan: next core (idx,val) strictly after own range ----
  int ri = fi; float rv = fv;
  for (int d = 1; d < 64; d <<= 1) {
    int ui = __shfl_down(ri, d); float uv = __shfl_down(rv, d);
    if (lane < 64 - d && ui < ri) { ri = ui; rv = uv; }
  }
  int Ri = __shfl_down(ri, 1); float Rv = __shfl_down(rv, 1);
  if (lane == 63) Ri = BIGI;
  if (lane == 0) { wri[wid] = ri; wrv[wid] = rv; }
  __syncthreads();
  for (int w2 = wid + 1; w2 < 16; ++w2)
    if (wri[w2] < Ri) { Ri = wri[w2]; Rv = wrv[w2]; }

  // ---- 9. single forward label pass (core + border resolved inline) ----
  float P  = sp.h ? sp.l : -INFINITY;       // last core value seen so far
  int starts = sp.h ? (sp.c + 1) : 0;       // #clusters so far; starts-1 = label of P
  unsigned pw[8];
  #pragma unroll
  for (int s = 0; s < VPT; ++s) {
    float xi = xs[phys(p0 + s)];
    int lb;
    if ((coremask >> s) & 1u) {
      if ((xi - P) > EPSF) ++starts;
      P = xi;
      lb = starts - 1;
    } else {
      float dl = xi - P;                    // +inf when no left core
      unsigned hb = coremask >> (s + 1);    // later cores within this thread
      float Rv2; bool has;
      if (hb) { int j = s + 1 + __builtin_ctz(hb); Rv2 = xs[phys(p0 + j)]; has = true; }
      else    { Rv2 = Rv; has = (Ri < NPTS); }
      float dr = has ? (Rv2 - xi) : INFINITY;
      lb = -1;
      if (fminf(dl, dr) <= EPSF)
        lb = (dl <= dr) ? (starts - 1)
                        : (starts - 1 + (((Rv2 - P) > EPSF) ? 1 : 0)); // next core's id
    }
    unsigned u16v = (unsigned)(unsigned short)(short)lb;
    if (s & 1) pw[s >> 1] |= u16v << 16;
    else       pw[s >> 1]  = u16v;
  }
  if (tid == TB - 1) nclg[bd] = starts;
  {
    uint4* dst = (uint4*)(lab + p0);
    dst[0] = make_uint4(pw[0], pw[1], pw[2], pw[3]);
    dst[1] = make_uint4(pw[4], pw[5], pw[6], pw[7]);
  }
  __syncthreads();   // all lab stores drained (barrier implies vmcnt(0))

  // ---- 10. unsort: bin-start walk per original element; coalesced writes ----
  #pragma unroll
  for (int s = 0; s < VPT; ++s) {
    int n = tid + s * TB;
    float vv = x[n];                        // re-read (L2/L3-hot)
    int b = binof(vv, mn, inv);
    int p = b ? pk_get(offsp[(b - 1) >> 1], (b - 1) & 1) : 0;
    while (xs[phys(p)] < vv) ++p;           // equal values share a label
    labels[(size_t)bd * NPTS + n] = lab[p];
  }
}

// ------- per-batch cluster-count prefix + inverse col->(dim,label) map -------
__global__ void koffs(const int* __restrict__ ncl, int* __restrict__ colmap) {
  int lane = threadIdx.x & 63;
  int b    = threadIdx.x >> 6;
  int vcnt = ncl[b * 64 + lane];
  int incl = vcnt;
  for (int d = 1; d < 64; d <<= 1) {
    int u = __shfl_up(incl, d);
    if (lane >= d) incl += u;
  }
  int off = incl - vcnt;
  int* cm = colmap + b * NCMAX;
  for (int k = lane; k < NCMAX; k += 64) cm[k] = -1;
  __syncthreads();
  for (int k = 0; k < vcnt; ++k) {
    int col = off + k;
    if (col < NCMAX) cm[col] = lane | (k << 8);
  }
}

// ---------------- fused zero+scatter: write full output rows ----------------
__global__ void __launch_bounds__(TB) kout(const short* __restrict__ labels,
                                           const int* __restrict__ colmap,
                                           float* __restrict__ out) {
  const int tid  = threadIdx.x;
  const int lane = tid & 63;
  const int wid  = tid >> 6;
  const int b    = blockIdx.x >> 5;
  const int n0   = (blockIdx.x & 31) * 512 + wid * 32;

  int cm[8];
  const int* cmb = colmap + b * NCMAX;
  #pragma unroll
  for (int k = 0; k < 8; ++k) {
    int col = (k < 4) ? (lane * 4 + k) : (256 + lane * 4 + (k - 4));
    cm[k] = cmb[col];
  }
  const short* lb_b = labels + (size_t)b * NDIM * NPTS;

  for (int r = 0; r < 32; ++r) {
    int n = n0 + r;
    float o[8];
    #pragma unroll
    for (int k = 0; k < 8; ++k) {
      int m = cm[k];
      float val = 0.f;
      if (m >= 0) {
        int d  = m & 255;
        int kk = m >> 8;
        val = (lb_b[(size_t)d * NPTS + n] == (short)kk) ? 1.0f : 0.0f;
      }
      o[k] = val;
    }
    float4* op = (float4*)(out + ((size_t)b * NPTS + n) * NCMAX);
    op[lane]      = make_float4(o[0], o[1], o[2], o[3]);
    op[64 + lane] = make_float4(o[4], o[5], o[6], o[7]);
  }
}

extern "C" void kernel_launch(void* const* d_in, const int* in_sizes, int n_in,
                              void* d_out, int out_size, void* d_ws, size_t ws_size,
                              hipStream_t stream) {
  const float* feat = (const float*)d_in[0];
  float* out = (float*)d_out;

  char* ws = (char*)d_ws;
  size_t xt_b   = (size_t)NBATCH * NPTS * NDIM * 4;   // 32 MB
  size_t lbl_b  = (size_t)NBATCH * NPTS * NDIM * 2;   // 16 MB
  float* xt     = (float*)ws;
  short* labels = (short*)(ws + xt_b);
  short* labg   = (short*)(ws + xt_b + lbl_b);        // 16 MB sorted-order label scratch
  int*   ncl    = (int*)(ws + xt_b + 2 * lbl_b);
  int*   colmap = ncl + NBATCH * NDIM;

  ktrans  <<<NBATCH * (NPTS / 64), 256, 0, stream>>>(feat, xt);
  kdbscan <<<NBATCH * NDIM, TB, 0, stream>>>(xt, labels, labg, ncl);
  koffs   <<<1, 512, 0, stream>>>(ncl, colmap);
  kout    <<<NBATCH * 32, TB, 0, stream>>>(labels, colmap, out);
}